// Round 16
// baseline (236.389 us; speedup 1.0000x reference)
//
#include <hip/hip_runtime.h>
#include <stdint.h>

typedef unsigned short u16;
typedef __attribute__((ext_vector_type(8))) short bf16x8;
typedef __attribute__((ext_vector_type(4))) float f32x4;

#define LOG2E 1.4426950408889634f
#define QSCALE (0.125f * LOG2E)

__device__ __forceinline__ float bf2f(u16 u) {
    union { uint32_t i; float f; } v; v.i = ((uint32_t)u) << 16; return v.f;
}
__device__ __forceinline__ u16 f2bf(float f) {
    union { float f; uint32_t i; } v; v.f = f;
    uint32_t i = v.i;
    return (u16)((i + 0x7FFF + ((i >> 16) & 1)) >> 16);
}
__device__ __forceinline__ uint32_t cvt_pk_bf16(float a, float b) {
    uint32_t r;
    asm("v_cvt_pk_bf16_f32 %0, %1, %2" : "=v"(r) : "v"(a), "v"(b));
    return r;
}
__device__ __forceinline__ int imin(int a, int b) { return a < b ? a : b; }
__device__ __forceinline__ int imax(int a, int b) { return a > b ? a : b; }

__device__ __forceinline__ void gl_lds16(const void* g, void* l) {
    __builtin_amdgcn_global_load_lds(
        (const __attribute__((address_space(1))) uint32_t*)g,
        (__attribute__((address_space(3))) uint32_t*)l, 16, 0, 0);
}

// exp2(t) for |t| <= 0.19, tuned quadratic (odd-term absorbed into linear coeff);
// rel err <= ~1e-4, and the common-mode part cancels in softmax normalization.
__device__ __forceinline__ float exp2q(float t) {
    const float a = 0.6946474805f;
    const float b = 0.2402265069f;
    return fmaf(fmaf(b, t, a), t, 1.0f);
}

union U8 { bf16x8 v; uint32_t u[4]; };

// ---------------------------------------------------------------- fused prep
// blocks [0,288): rope table; [288,4896): x->bf16; [4896,5216): weight transpose.
__global__ void k_prep(const float* __restrict__ x,
                       const float* __restrict__ Wq, const float* __restrict__ Wk,
                       const float* __restrict__ Wv1, const float* __restrict__ Wv2,
                       const float* __restrict__ Wp,
                       float* __restrict__ tab, u16* __restrict__ xb,
                       u16* __restrict__ WCT, u16* __restrict__ WPT) {
    __shared__ u16 tile[64][65];
    int bid = blockIdx.x;
    if (bid < 288) {
        int t = bid * 256 + threadIdx.x;
        if (t >= 2304 * 32) return;
        int n = t >> 5, j = t & 31;
        int gh = n / 48, gw = n % 48;
        float f = (float)(j & 15);
        float coord = (j < 16) ? (float)gh : (float)gw;
        float inv = exp2f(-f * (13.287712379549449f / 16.0f)); // 10000^(-f/16)
        float th = coord * inv;
        tab[t * 2 + 0] = cosf(th);
        tab[t * 2 + 1] = sinf(th);
    } else if (bid < 4896) {
        int t = (bid - 288) * 256 + threadIdx.x;
        if (t >= 9216 * 512 / 4) return;
        float4 v = ((const float4*)x)[t];
        ushort4 o;
        o.x = f2bf(v.x); o.y = f2bf(v.y); o.z = f2bf(v.z); o.w = f2bf(v.w);
        ((ushort4*)xb)[t] = o;
    } else {
        int jb = bid - 4896;               // [0,320)
        int n0 = (jb % 40) * 64;
        int k0 = (jb / 40) * 64;
        int c = threadIdx.x & 63;
        int rr = threadIdx.x >> 6;
        const float* src; int stride; int roff; u16* dst; int nb;
        if (n0 < 1024)      { src = Wq;  stride = 1024; roff = 0;    dst = WCT; nb = n0; }
        else if (n0 < 1536) { src = Wk;  stride = 512;  roff = 1024; dst = WCT; nb = n0; }
        else if (n0 < 1792) { src = Wv1; stride = 256;  roff = 1536; dst = WCT; nb = n0; }
        else if (n0 < 2048) { src = Wv2; stride = 256;  roff = 1792; dst = WCT; nb = n0; }
        else                { src = Wp;  stride = 512;  roff = 2048; dst = WPT; nb = n0 - 2048; }
        int scol = n0 + c - roff;
#pragma unroll
        for (int i = 0; i < 16; ++i) {
            int k = rr * 16 + i;
            tile[c][k] = f2bf(src[(size_t)(k0 + k) * stride + scol]);
        }
        __syncthreads();
        int kk = threadIdx.x & 63;
        int c4 = threadIdx.x >> 6;
#pragma unroll
        for (int i = 0; i < 16; ++i) {
            int nl = c4 * 16 + i;
            dst[(size_t)(nb + nl) * 512 + k0 + kk] = tile[nl][kk];
        }
    }
}

// ---------------------------------------------------------------- fused QKV GEMM
// C = XB * WCT^T with fused epilogue: Q cols -> L2norm+RoPE (scaled by QSCALE) -> Q1/Q2;
// K cols -> L2norm+RoPE -> KF fragment layout; V cols -> VF fragment layout.
// XCD-aware remap: each XCD owns 9 contiguous m-tiles x all 16 n-tiles.
__global__ __launch_bounds__(256) void k_gemm_qkv(
    const u16* __restrict__ A, const u16* __restrict__ BT,
    const float* __restrict__ tab,
    u16* __restrict__ Q1, u16* __restrict__ Q2,
    u16* __restrict__ KF1, u16* __restrict__ KF2,
    u16* __restrict__ VF1, u16* __restrict__ VF2) {
    __shared__ u16 Asw[128 * 64];
    __shared__ u16 Bsw[128 * 64];
    const int K = 512;
    int id = blockIdx.x + 16 * blockIdx.y;        // [0,1152)
    int l = (id & 7) * 144 + (id >> 3);           // bijective XCD remap
    int n0 = (l & 15) * 128;
    int m0 = (l >> 4) * 128;
    int tid = threadIdx.x;
    int lane = tid & 63, w = tid >> 6;
    int wm = w >> 1, wn = w & 1;
    int li = lane & 15, g = lane >> 4;
    f32x4 zero4 = {0.f, 0.f, 0.f, 0.f};
    f32x4 acc[4][4];
#pragma unroll
    for (int mi = 0; mi < 4; ++mi)
#pragma unroll
        for (int ni = 0; ni < 4; ++ni) acc[mi][ni] = zero4;

    for (int k0 = 0; k0 < K; k0 += 64) {
        __syncthreads();
#pragma unroll
        for (int p = 0; p < 4; ++p) {
            int cidx = p * 256 + tid;
            int r = cidx >> 3, j = cidx & 7;
            int jj = j ^ (r & 7);
            gl_lds16(A  + (size_t)(m0 + r) * K + k0 + jj * 8, (char*)Asw + cidx * 16);
            gl_lds16(BT + (size_t)(n0 + r) * K + k0 + jj * 8, (char*)Bsw + cidx * 16);
        }
        __syncthreads();
#pragma unroll
        for (int ks = 0; ks < 2; ++ks) {
            bf16x8 af[4], bfr[4];
#pragma unroll
            for (int mi = 0; mi < 4; ++mi) {
                int r = wm * 64 + mi * 16 + li;
                int kc = ks * 4 + g;
                af[mi] = *(const bf16x8*)((const char*)Asw + r * 128 + ((kc ^ (r & 7)) * 16));
            }
#pragma unroll
            for (int ni = 0; ni < 4; ++ni) {
                int r = wn * 64 + ni * 16 + li;
                int kc = ks * 4 + g;
                bfr[ni] = *(const bf16x8*)((const char*)Bsw + r * 128 + ((kc ^ (r & 7)) * 16));
            }
#pragma unroll
            for (int mi = 0; mi < 4; ++mi)
#pragma unroll
                for (int ni = 0; ni < 4; ++ni)
                    acc[mi][ni] = __builtin_amdgcn_mfma_f32_16x16x32_bf16(af[mi], bfr[ni], acc[mi][ni], 0, 0, 0);
        }
    }

    // ------------- fused epilogue -------------
    int colbase = n0 + wn * 64;           // head-aligned 64-col block
    int b = m0 / 2304;                    // tile never straddles batch (2304 % 128 == 0)
    int nbase = (m0 % 2304) + wm * 64;

    if (colbase < 1536) {
        // Q or K: L2 norm over the 64-dim head vector + RoPE, then write.
        u16* out; int isK; size_t hb;
        if (colbase < 1024) {
            out = (colbase < 512) ? Q1 : Q2;
            int h = (colbase >> 6) & 7;
            hb = (size_t)(b * 8 + h) * 2304;
            isK = 0;
        } else {
            out = (colbase < 1280) ? KF1 : KF2;
            int hkv = ((colbase - 1024) >> 6) & 3;
            hb = (size_t)(b * 4 + hkv) * 48;
            isK = 1;
        }
        float qs = isK ? 1.0f : QSCALE;   // fold softmax scale into Q only
#pragma unroll
        for (int mi = 0; mi < 4; ++mi) {
            float rsq[4];
#pragma unroll
            for (int r = 0; r < 4; ++r) {
                float ss = 0.f;
#pragma unroll
                for (int ni = 0; ni < 4; ++ni) ss += acc[mi][ni][r] * acc[mi][ni][r];
                ss += __shfl_xor(ss, 1, 64);
                ss += __shfl_xor(ss, 2, 64);
                ss += __shfl_xor(ss, 4, 64);
                ss += __shfl_xor(ss, 8, 64);
                rsq[r] = qs / sqrtf(ss + 1e-12f);
            }
#pragma unroll
            for (int r = 0; r < 4; ++r) {
                int n = nbase + mi * 16 + g * 4 + r;
                float2 cs0 = *(const float2*)(tab + ((size_t)n * 32 + li) * 2);
                float2 cs1 = *(const float2*)(tab + ((size_t)n * 32 + 16 + li) * 2);
                float y[4];
#pragma unroll
                for (int ni = 0; ni < 4; ++ni) {
                    float c = (ni & 1) ? cs1.x : cs0.x;
                    float s = (ni & 1) ? cs1.y : cs0.y;
                    float p = acc[mi][ni ^ 2][r];
                    float t = (ni < 2) ? (acc[mi][ni][r] * c - p * s)
                                       : (acc[mi][ni][r] * c + p * s);
                    y[ni] = t * rsq[r];
                }
                if (!isK) {
                    size_t obase = (hb + n) * 64;
#pragma unroll
                    for (int ni = 0; ni < 4; ++ni)
                        out[obase + ni * 16 + li] = f2bf(y[ni]);
                } else {
                    int kh = n / 48, r48 = n % 48;
                    int kt = r48 >> 4, lq = r48 & 15;
                    size_t base = (hb + kh) * 3072;
#pragma unroll
                    for (int ni = 0; ni < 4; ++ni) {
                        int sC = ni >> 1;
                        int gg = ((ni & 1) << 1) + (li >> 3);
                        int e = li & 7;
                        out[base + (size_t)(((kt * 2 + sC) * 64 + gg * 16 + lq) * 8 + e)] = f2bf(y[ni]);
                    }
                }
            }
        }
    } else {
        // V: no norm/rope; pack straight into VF fragment layout.
        u16* out = (colbase < 1792) ? VF1 : VF2;
        int hkv = ((colbase - 1536) >> 6) & 3;
        size_t hb = (size_t)(b * 4 + hkv) * 48;
#pragma unroll
        for (int mi = 0; mi < 4; ++mi) {
            int n4 = nbase + mi * 16 + g * 4;       // 4 consecutive tokens, 4-aligned
            int kh = n4 / 48, r48 = n4 % 48;
            int grp = r48 >> 2;
            int kt = grp >> 2, gp = grp & 3;
            size_t base = (hb + kh) * 3072;
#pragma unroll
            for (int ni = 0; ni < 4; ++ni) {
                uint2 val;
                val.x = cvt_pk_bf16(acc[mi][ni][0], acc[mi][ni][1]);
                val.y = cvt_pk_bf16(acc[mi][ni][2], acc[mi][ni][3]);
                *(uint2*)(out + base + (size_t)(((ni * 3 + kt) * 64 + gp * 16 + li) * 4)) = val;
            }
        }
    }
}

// ---------------------------------------------------------------- out GEMM, 64x64 tiles
// XCD-aware remap: each XCD owns 18 contiguous m-tiles x all 8 n-tiles.
__global__ __launch_bounds__(256) void k_gemm_o64(
    const u16* __restrict__ A, const u16* __restrict__ BT,
    float* __restrict__ Cout, const float* __restrict__ bias) {
    __shared__ u16 Asw[64 * 64];
    __shared__ u16 Bsw[64 * 64];
    const int K = 512;
    const int N = 512;
    int id = blockIdx.x + 8 * blockIdx.y;         // [0,1152)
    int l = (id & 7) * 144 + (id >> 3);           // bijective XCD remap
    int n0 = (l & 7) * 64;
    int m0 = (l >> 3) * 64;
    int tid = threadIdx.x;
    int lane = tid & 63, w = tid >> 6;
    int wm = w >> 1, wn = w & 1;
    int li = lane & 15, g = lane >> 4;
    f32x4 zero4 = {0.f, 0.f, 0.f, 0.f};
    f32x4 acc[2][2];
#pragma unroll
    for (int mi = 0; mi < 2; ++mi)
#pragma unroll
        for (int ni = 0; ni < 2; ++ni) acc[mi][ni] = zero4;

    for (int k0 = 0; k0 < K; k0 += 64) {
        __syncthreads();
#pragma unroll
        for (int p = 0; p < 2; ++p) {
            int ci = p * 256 + tid;
            int r = ci >> 3, j = ci & 7;
            int jj = j ^ (r & 7);
            gl_lds16(A  + (size_t)(m0 + r) * K + k0 + jj * 8, (char*)Asw + ci * 16);
            gl_lds16(BT + (size_t)(n0 + r) * K + k0 + jj * 8, (char*)Bsw + ci * 16);
        }
        __syncthreads();
#pragma unroll
        for (int ks = 0; ks < 2; ++ks) {
            bf16x8 af[2], bfr[2];
#pragma unroll
            for (int mi = 0; mi < 2; ++mi) {
                int r = wm * 32 + mi * 16 + li;
                int kc = ks * 4 + g;
                af[mi] = *(const bf16x8*)((const char*)Asw + r * 128 + ((kc ^ (r & 7)) * 16));
            }
#pragma unroll
            for (int ni = 0; ni < 2; ++ni) {
                int r = wn * 32 + ni * 16 + li;
                int kc = ks * 4 + g;
                bfr[ni] = *(const bf16x8*)((const char*)Bsw + r * 128 + ((kc ^ (r & 7)) * 16));
            }
#pragma unroll
            for (int mi = 0; mi < 2; ++mi)
#pragma unroll
                for (int ni = 0; ni < 2; ++ni)
                    acc[mi][ni] = __builtin_amdgcn_mfma_f32_16x16x32_bf16(af[mi], bfr[ni], acc[mi][ni], 0, 0, 0);
        }
    }
#pragma unroll
    for (int mi = 0; mi < 2; ++mi)
#pragma unroll
        for (int ni = 0; ni < 2; ++ni) {
#pragma unroll
            for (int r = 0; r < 4; ++r) {
                int row = m0 + wm * 32 + mi * 16 + g * 4 + r;
                int col = n0 + wn * 32 + ni * 16 + li;
                Cout[(size_t)row * N + col] = acc[mi][ni][r] + bias[col];
            }
        }
}

// ------------------------------------------------- differential windowed attention
// wave = (b,hkv,qh,mu,beta) handling both h2 heads; all loads lane-contiguous.
// r16: simple single-buffered loads (drop manual prefetch) + __launch_bounds__(128,5)
// to unlock a 5th wave/SIMD — trade ILP for TLP at the latency-bound operating point.
// [FROZEN structure otherwise]
template <int A, int NTT>
__device__ __forceinline__ void load_k(const u16* __restrict__ kb, bf16x8 (&kf)[NTT][2], int lane) {
#pragma unroll
    for (int t = 0; t < NTT; ++t)
#pragma unroll
        for (int s = 0; s < 2; ++s)
            kf[t][s] = *(const bf16x8*)(kb + ((A + t) * 2 + s) * 512 + lane * 8);
}

template <int A, int NTT>
__device__ __forceinline__ void load_v(const u16* __restrict__ vb, uint2 (&ch)[4][NTT], int lane) {
#pragma unroll
    for (int dt = 0; dt < 4; ++dt)
#pragma unroll
        for (int t = 0; t < NTT; ++t)
            ch[dt][t] = *(const uint2*)(vb + ((dt * 3 + A + t) * 64 + lane) * 4);
}

template <int A, int NTT>
__device__ __forceinline__ void attn_core(
    const bf16x8 (&kf)[NTT][2], const uint2 (&ch)[4][NTT],
    const bf16x8 (&qf)[2][2], const float (&bmul)[3][4],
    f32x4 (&Oa)[2][4], float (&sum)[2]) {
    __builtin_amdgcn_s_setprio(1);
    U8 pa0[2], pa1[2];
#pragma unroll
    for (int h = 0; h < 2; ++h) {
        f32x4 S[NTT];
#pragma unroll
        for (int t = 0; t < NTT; ++t) {
            f32x4 z = {0.f, 0.f, 0.f, 0.f};
            z = __builtin_amdgcn_mfma_f32_16x16x32_bf16(kf[t][0], qf[h][0], z, 0, 0, 0);
            S[t] = __builtin_amdgcn_mfma_f32_16x16x32_bf16(kf[t][1], qf[h][1], z, 0, 0, 0);
        }
        uint32_t pk[NTT][2];
#pragma unroll
        for (int t = 0; t < NTT; ++t)
#pragma unroll
            for (int rp = 0; rp < 2; ++rp) {
                float p0 = exp2q(S[t][2 * rp])     * bmul[A + t][2 * rp];
                float p1 = exp2q(S[t][2 * rp + 1]) * bmul[A + t][2 * rp + 1];
                sum[h] += p0 + p1;
                pk[t][rp] = cvt_pk_bf16(p0, p1);
            }
        pa0[h].u[0] = pk[0][0]; pa0[h].u[1] = pk[0][1];
        pa0[h].u[2] = pk[1][0]; pa0[h].u[3] = pk[1][1];
        if (NTT == 3) { pa1[h].u[0] = pk[2][0]; pa1[h].u[1] = pk[2][1]; pa1[h].u[2] = 0; pa1[h].u[3] = 0; }
    }
#pragma unroll
    for (int dt = 0; dt < 4; ++dt) {
        union { bf16x8 v; uint2 q[2]; } vf0, vf1;
        vf0.q[0] = ch[dt][0]; vf0.q[1] = ch[dt][1];
        if (NTT == 3) { vf1.q[0] = ch[dt][2]; vf1.q[1] = ch[dt][2]; } // upper half x zero P
#pragma unroll
        for (int h = 0; h < 2; ++h) {
            Oa[h][dt] = __builtin_amdgcn_mfma_f32_16x16x32_bf16(pa0[h].v, vf0.v, Oa[h][dt], 0, 0, 0);
            if (NTT == 3)
                Oa[h][dt] = __builtin_amdgcn_mfma_f32_16x16x32_bf16(pa1[h].v, vf1.v, Oa[h][dt], 0, 0, 0);
        }
    }
    __builtin_amdgcn_s_setprio(0);
}

template <int A, int NTT>
__device__ __forceinline__ void run_simple(
    const u16* __restrict__ kp, const u16* __restrict__ vp, int n,
    const bf16x8 (&qf)[2][2], const float (&bmul)[3][4],
    f32x4 (&Oa)[2][4], float (&sum)[2], int lane) {
    for (int i = 0; i < n; ++i) {
        bf16x8 kf[NTT][2];
        uint2 ch[4][NTT];
        load_k<A, NTT>(kp, kf, lane);
        load_v<A, NTT>(vp, ch, lane);
        attn_core<A, NTT>(kf, ch, qf, bmul, Oa, sum);
        kp += 3072; vp += 3072;
    }
}

__global__ __launch_bounds__(128, 5) void k_attention(
    const u16* __restrict__ Q1, const u16* __restrict__ Q2,
    const u16* __restrict__ KF1, const u16* __restrict__ KF2,
    const u16* __restrict__ VF1, const u16* __restrict__ VF2,
    const float* __restrict__ lambda_p, u16* __restrict__ AOUT) {
    __shared__ float obuf[2][16][64];
    int tid = threadIdx.x;
    int lane = tid & 63, beta = tid >> 6;
    int li = lane & 15, g = lane >> 4;
    // XCD swizzle + central-first qh ordering (long blocks launch first)
    int hw = blockIdx.x;
    int l = (hw & 7) * 288 + (hw >> 3);
    int mu = l % 3, j = (l / 3) % 48, kvb = l / 144;
    int m2 = j >> 1;
    int qh = (j & 1) ? (23 - m2) : (24 + m2);   // bijective [0,48) -> [0,48)
    int hkv = kvb & 3, b = kvb >> 2;

    const u16* Qb = beta ? Q2 : Q1;

    bf16x8 qf[2][2];
#pragma unroll
    for (int h2 = 0; h2 < 2; ++h2)
#pragma unroll
        for (int s = 0; s < 2; ++s)
            qf[h2][s] = *(const bf16x8*)(Qb + ((size_t)(b * 8 + hkv * 2 + h2) * 2304
                            + qh * 48 + mu * 16 + li) * 64 + s * 32 + g * 8);

    float bmul[3][4];
    int qw = mu * 16 + li;
#pragma unroll
    for (int t = 0; t < 3; ++t)
#pragma unroll
        for (int r = 0; r < 4; ++r) {
            int kw = t * 16 + 4 * g + r;
            int dw = qw - kw; if (dw < 0) dw = -dw;
            bmul[t][r] = (dw <= 12) ? 1.0f : 0.0f;
        }

    f32x4 zero4 = {0.f, 0.f, 0.f, 0.f};
    f32x4 Oa[2][4];
#pragma unroll
    for (int h = 0; h < 2; ++h)
#pragma unroll
        for (int dt = 0; dt < 4; ++dt) Oa[h][dt] = zero4;
    float sum[2] = {0.f, 0.f};

    int kh0 = imax(0, qh - 12), kh1 = imin(47, qh + 12);
    int niter = kh1 - kh0 + 1;
    const u16* kp = (beta ? KF2 : KF1) + ((size_t)kvb * 48 + kh0) * 3072;
    const u16* vp = (beta ? VF2 : VF1) + ((size_t)kvb * 48 + kh0) * 3072;

    if (mu == 1)      run_simple<0, 3>(kp, vp, niter, qf, bmul, Oa, sum, lane);
    else if (mu == 0) run_simple<0, 2>(kp, vp, niter, qf, bmul, Oa, sum, lane);
    else              run_simple<1, 2>(kp, vp, niter, qf, bmul, Oa, sum, lane);

    // finish row-sums: reduce over g groups, then fetch per-(4g+r) sums
    float inv[2][4];
#pragma unroll
    for (int h = 0; h < 2; ++h) {
        float s = sum[h];
        s += __shfl_xor(s, 16, 64);
        s += __shfl_xor(s, 32, 64);   // every lane: rowsum for q = li
#pragma unroll
        for (int r = 0; r < 4; ++r)
            inv[h][r] = 1.0f / __shfl(s, 4 * g + r, 64);
    }

    if (beta == 1) {
#pragma unroll
        for (int h = 0; h < 2; ++h)
#pragma unroll
            for (int dt = 0; dt < 4; ++dt)
#pragma unroll
                for (int r = 0; r < 4; ++r)
                    obuf[h][4 * g + r][dt * 16 + li] = Oa[h][dt][r] * inv[h][r];
    }
    __syncthreads();
    if (beta == 0) {
#pragma unroll
        for (int h = 0; h < 2; ++h) {
            float lam = 1.0f / (1.0f + expf(-lambda_p[hkv * 2 + h]));
#pragma unroll
            for (int dt = 0; dt < 4; ++dt)
#pragma unroll
                for (int r = 0; r < 4; ++r) {
                    float o1 = Oa[h][dt][r] * inv[h][r];
                    float o2 = obuf[h][4 * g + r][dt * 16 + li];
                    int n = qh * 48 + mu * 16 + 4 * g + r;
                    int colc = (hkv * 2 + h) * 64 + dt * 16 + li;
                    AOUT[((size_t)(b * 2304 + n)) * 512 + colc] = f2bf(o1 - lam * o2);
                }
        }
    }
}

// ---------------------------------------------------------------- launcher
extern "C" void kernel_launch(void* const* d_in, const int* in_sizes, int n_in,
                              void* d_out, int out_size, void* d_ws, size_t ws_size,
                              hipStream_t stream) {
    const float* x        = (const float*)d_in[0];
    const float* Wq       = (const float*)d_in[1];
    const float* Wk       = (const float*)d_in[2];
    const float* Wv1      = (const float*)d_in[3];
    const float* Wv2      = (const float*)d_in[4];
    const float* lambda_p = (const float*)d_in[5];
    const float* Wp       = (const float*)d_in[6];
    const float* bp       = (const float*)d_in[7];

    char* ws = (char*)d_ws;
    size_t off = 0;
    auto alloc = [&](size_t bytes) { char* p = ws + off; off += (bytes + 255) & ~(size_t)255; return p; };
    float* rope = (float*)alloc((size_t)2304 * 32 * 2 * 4);
    u16* XB     = (u16*)alloc((size_t)9216 * 512 * 2);
    u16* WCT    = (u16*)alloc((size_t)2048 * 512 * 2);
    u16* WPT    = (u16*)alloc((size_t)512 * 512 * 2);
    u16* Q1     = (u16*)alloc((size_t)4 * 8 * 2304 * 64 * 2);
    u16* Q2     = (u16*)alloc((size_t)4 * 8 * 2304 * 64 * 2);
    u16* KF1    = (u16*)alloc((size_t)16 * 48 * 3072 * 2);
    u16* KF2    = (u16*)alloc((size_t)16 * 48 * 3072 * 2);
    u16* VF1    = (u16*)alloc((size_t)16 * 48 * 3072 * 2);
    u16* VF2    = (u16*)alloc((size_t)16 * 48 * 3072 * 2);
    u16* AOUT   = (u16*)alloc((size_t)9216 * 512 * 2);

    k_prep<<<5216, 256, 0, stream>>>(x, Wq, Wk, Wv1, Wv2, Wp, rope, XB, WCT, WPT);
    k_gemm_qkv<<<dim3(16, 72), 256, 0, stream>>>(XB, WCT, rope, Q1, Q2, KF1, KF2, VF1, VF2);
    k_attention<<<2304, 128, 0, stream>>>(Q1, Q2, KF1, KF2, VF1, VF2, lambda_p, AOUT);
    k_gemm_o64<<<dim3(8, 144), 256, 0, stream>>>(AOUT, WPT, (float*)d_out, bp);
}

// Round 17
// 120.347 us; speedup vs baseline: 1.9642x; 1.9642x over previous
//
#include <hip/hip_runtime.h>
#include <stdint.h>

typedef unsigned short u16;
typedef __attribute__((ext_vector_type(8))) short bf16x8;
typedef __attribute__((ext_vector_type(4))) float f32x4;

#define LOG2E 1.4426950408889634f
#define QSCALE (0.125f * LOG2E)

__device__ __forceinline__ float bf2f(u16 u) {
    union { uint32_t i; float f; } v; v.i = ((uint32_t)u) << 16; return v.f;
}
__device__ __forceinline__ u16 f2bf(float f) {
    union { float f; uint32_t i; } v; v.f = f;
    uint32_t i = v.i;
    return (u16)((i + 0x7FFF + ((i >> 16) & 1)) >> 16);
}
__device__ __forceinline__ uint32_t cvt_pk_bf16(float a, float b) {
    uint32_t r;
    asm("v_cvt_pk_bf16_f32 %0, %1, %2" : "=v"(r) : "v"(a), "v"(b));
    return r;
}
__device__ __forceinline__ int imin(int a, int b) { return a < b ? a : b; }
__device__ __forceinline__ int imax(int a, int b) { return a > b ? a : b; }

__device__ __forceinline__ void gl_lds16(const void* g, void* l) {
    __builtin_amdgcn_global_load_lds(
        (const __attribute__((address_space(1))) uint32_t*)g,
        (__attribute__((address_space(3))) uint32_t*)l, 16, 0, 0);
}

// exp2(t) for |t| <= 0.19, tuned quadratic (odd-term absorbed into linear coeff);
// rel err <= ~1e-4, and the common-mode part cancels in softmax normalization.
__device__ __forceinline__ float exp2q(float t) {
    const float a = 0.6946474805f;
    const float b = 0.2402265069f;
    return fmaf(fmaf(b, t, a), t, 1.0f);
}

union U8 { bf16x8 v; uint32_t u[4]; };

// ---------------------------------------------------------------- fused prep
// blocks [0,288): rope table; [288,4896): x->bf16; [4896,5216): weight transpose.
__global__ void k_prep(const float* __restrict__ x,
                       const float* __restrict__ Wq, const float* __restrict__ Wk,
                       const float* __restrict__ Wv1, const float* __restrict__ Wv2,
                       const float* __restrict__ Wp,
                       float* __restrict__ tab, u16* __restrict__ xb,
                       u16* __restrict__ WCT, u16* __restrict__ WPT) {
    __shared__ u16 tile[64][65];
    int bid = blockIdx.x;
    if (bid < 288) {
        int t = bid * 256 + threadIdx.x;
        if (t >= 2304 * 32) return;
        int n = t >> 5, j = t & 31;
        int gh = n / 48, gw = n % 48;
        float f = (float)(j & 15);
        float coord = (j < 16) ? (float)gh : (float)gw;
        float inv = exp2f(-f * (13.287712379549449f / 16.0f)); // 10000^(-f/16)
        float th = coord * inv;
        tab[t * 2 + 0] = cosf(th);
        tab[t * 2 + 1] = sinf(th);
    } else if (bid < 4896) {
        int t = (bid - 288) * 256 + threadIdx.x;
        if (t >= 9216 * 512 / 4) return;
        float4 v = ((const float4*)x)[t];
        ushort4 o;
        o.x = f2bf(v.x); o.y = f2bf(v.y); o.z = f2bf(v.z); o.w = f2bf(v.w);
        ((ushort4*)xb)[t] = o;
    } else {
        int jb = bid - 4896;               // [0,320)
        int n0 = (jb % 40) * 64;
        int k0 = (jb / 40) * 64;
        int c = threadIdx.x & 63;
        int rr = threadIdx.x >> 6;
        const float* src; int stride; int roff; u16* dst; int nb;
        if (n0 < 1024)      { src = Wq;  stride = 1024; roff = 0;    dst = WCT; nb = n0; }
        else if (n0 < 1536) { src = Wk;  stride = 512;  roff = 1024; dst = WCT; nb = n0; }
        else if (n0 < 1792) { src = Wv1; stride = 256;  roff = 1536; dst = WCT; nb = n0; }
        else if (n0 < 2048) { src = Wv2; stride = 256;  roff = 1792; dst = WCT; nb = n0; }
        else                { src = Wp;  stride = 512;  roff = 2048; dst = WPT; nb = n0 - 2048; }
        int scol = n0 + c - roff;
#pragma unroll
        for (int i = 0; i < 16; ++i) {
            int k = rr * 16 + i;
            tile[c][k] = f2bf(src[(size_t)(k0 + k) * stride + scol]);
        }
        __syncthreads();
        int kk = threadIdx.x & 63;
        int c4 = threadIdx.x >> 6;
#pragma unroll
        for (int i = 0; i < 16; ++i) {
            int nl = c4 * 16 + i;
            dst[(size_t)(nb + nl) * 512 + k0 + kk] = tile[nl][kk];
        }
    }
}

// ---------------------------------------------------------------- fused QKV GEMM
// C = XB * WCT^T with fused epilogue: Q cols -> L2norm+RoPE (scaled by QSCALE) -> Q1/Q2;
// K cols -> L2norm+RoPE -> KF fragment layout; V cols -> VF fragment layout.
// XCD-aware remap: each XCD owns 9 contiguous m-tiles x all 16 n-tiles.
__global__ __launch_bounds__(256) void k_gemm_qkv(
    const u16* __restrict__ A, const u16* __restrict__ BT,
    const float* __restrict__ tab,
    u16* __restrict__ Q1, u16* __restrict__ Q2,
    u16* __restrict__ KF1, u16* __restrict__ KF2,
    u16* __restrict__ VF1, u16* __restrict__ VF2) {
    __shared__ u16 Asw[128 * 64];
    __shared__ u16 Bsw[128 * 64];
    const int K = 512;
    int id = blockIdx.x + 16 * blockIdx.y;        // [0,1152)
    int l = (id & 7) * 144 + (id >> 3);           // bijective XCD remap
    int n0 = (l & 15) * 128;
    int m0 = (l >> 4) * 128;
    int tid = threadIdx.x;
    int lane = tid & 63, w = tid >> 6;
    int wm = w >> 1, wn = w & 1;
    int li = lane & 15, g = lane >> 4;
    f32x4 zero4 = {0.f, 0.f, 0.f, 0.f};
    f32x4 acc[4][4];
#pragma unroll
    for (int mi = 0; mi < 4; ++mi)
#pragma unroll
        for (int ni = 0; ni < 4; ++ni) acc[mi][ni] = zero4;

    for (int k0 = 0; k0 < K; k0 += 64) {
        __syncthreads();
#pragma unroll
        for (int p = 0; p < 4; ++p) {
            int cidx = p * 256 + tid;
            int r = cidx >> 3, j = cidx & 7;
            int jj = j ^ (r & 7);
            gl_lds16(A  + (size_t)(m0 + r) * K + k0 + jj * 8, (char*)Asw + cidx * 16);
            gl_lds16(BT + (size_t)(n0 + r) * K + k0 + jj * 8, (char*)Bsw + cidx * 16);
        }
        __syncthreads();
#pragma unroll
        for (int ks = 0; ks < 2; ++ks) {
            bf16x8 af[4], bfr[4];
#pragma unroll
            for (int mi = 0; mi < 4; ++mi) {
                int r = wm * 64 + mi * 16 + li;
                int kc = ks * 4 + g;
                af[mi] = *(const bf16x8*)((const char*)Asw + r * 128 + ((kc ^ (r & 7)) * 16));
            }
#pragma unroll
            for (int ni = 0; ni < 4; ++ni) {
                int r = wn * 64 + ni * 16 + li;
                int kc = ks * 4 + g;
                bfr[ni] = *(const bf16x8*)((const char*)Bsw + r * 128 + ((kc ^ (r & 7)) * 16));
            }
#pragma unroll
            for (int mi = 0; mi < 4; ++mi)
#pragma unroll
                for (int ni = 0; ni < 4; ++ni)
                    acc[mi][ni] = __builtin_amdgcn_mfma_f32_16x16x32_bf16(af[mi], bfr[ni], acc[mi][ni], 0, 0, 0);
        }
    }

    // ------------- fused epilogue -------------
    int colbase = n0 + wn * 64;           // head-aligned 64-col block
    int b = m0 / 2304;                    // tile never straddles batch (2304 % 128 == 0)
    int nbase = (m0 % 2304) + wm * 64;

    if (colbase < 1536) {
        // Q or K: L2 norm over the 64-dim head vector + RoPE, then write.
        u16* out; int isK; size_t hb;
        if (colbase < 1024) {
            out = (colbase < 512) ? Q1 : Q2;
            int h = (colbase >> 6) & 7;
            hb = (size_t)(b * 8 + h) * 2304;
            isK = 0;
        } else {
            out = (colbase < 1280) ? KF1 : KF2;
            int hkv = ((colbase - 1024) >> 6) & 3;
            hb = (size_t)(b * 4 + hkv) * 48;
            isK = 1;
        }
        float qs = isK ? 1.0f : QSCALE;   // fold softmax scale into Q only
#pragma unroll
        for (int mi = 0; mi < 4; ++mi) {
            float rsq[4];
#pragma unroll
            for (int r = 0; r < 4; ++r) {
                float ss = 0.f;
#pragma unroll
                for (int ni = 0; ni < 4; ++ni) ss += acc[mi][ni][r] * acc[mi][ni][r];
                ss += __shfl_xor(ss, 1, 64);
                ss += __shfl_xor(ss, 2, 64);
                ss += __shfl_xor(ss, 4, 64);
                ss += __shfl_xor(ss, 8, 64);
                rsq[r] = qs / sqrtf(ss + 1e-12f);
            }
#pragma unroll
            for (int r = 0; r < 4; ++r) {
                int n = nbase + mi * 16 + g * 4 + r;
                float2 cs0 = *(const float2*)(tab + ((size_t)n * 32 + li) * 2);
                float2 cs1 = *(const float2*)(tab + ((size_t)n * 32 + 16 + li) * 2);
                float y[4];
#pragma unroll
                for (int ni = 0; ni < 4; ++ni) {
                    float c = (ni & 1) ? cs1.x : cs0.x;
                    float s = (ni & 1) ? cs1.y : cs0.y;
                    float p = acc[mi][ni ^ 2][r];
                    float t = (ni < 2) ? (acc[mi][ni][r] * c - p * s)
                                       : (acc[mi][ni][r] * c + p * s);
                    y[ni] = t * rsq[r];
                }
                if (!isK) {
                    size_t obase = (hb + n) * 64;
#pragma unroll
                    for (int ni = 0; ni < 4; ++ni)
                        out[obase + ni * 16 + li] = f2bf(y[ni]);
                } else {
                    int kh = n / 48, r48 = n % 48;
                    int kt = r48 >> 4, lq = r48 & 15;
                    size_t base = (hb + kh) * 3072;
#pragma unroll
                    for (int ni = 0; ni < 4; ++ni) {
                        int sC = ni >> 1;
                        int gg = ((ni & 1) << 1) + (li >> 3);
                        int e = li & 7;
                        out[base + (size_t)(((kt * 2 + sC) * 64 + gg * 16 + lq) * 8 + e)] = f2bf(y[ni]);
                    }
                }
            }
        }
    } else {
        // V: no norm/rope; pack straight into VF fragment layout.
        u16* out = (colbase < 1792) ? VF1 : VF2;
        int hkv = ((colbase - 1536) >> 6) & 3;
        size_t hb = (size_t)(b * 4 + hkv) * 48;
#pragma unroll
        for (int mi = 0; mi < 4; ++mi) {
            int n4 = nbase + mi * 16 + g * 4;       // 4 consecutive tokens, 4-aligned
            int kh = n4 / 48, r48 = n4 % 48;
            int grp = r48 >> 2;
            int kt = grp >> 2, gp = grp & 3;
            size_t base = (hb + kh) * 3072;
#pragma unroll
            for (int ni = 0; ni < 4; ++ni) {
                uint2 val;
                val.x = cvt_pk_bf16(acc[mi][ni][0], acc[mi][ni][1]);
                val.y = cvt_pk_bf16(acc[mi][ni][2], acc[mi][ni][3]);
                *(uint2*)(out + base + (size_t)(((ni * 3 + kt) * 64 + gp * 16 + li) * 4)) = val;
            }
        }
    }
}

// ---------------------------------------------------------------- out GEMM, 64x64 tiles
// XCD-aware remap: each XCD owns 18 contiguous m-tiles x all 8 n-tiles.
__global__ __launch_bounds__(256) void k_gemm_o64(
    const u16* __restrict__ A, const u16* __restrict__ BT,
    float* __restrict__ Cout, const float* __restrict__ bias) {
    __shared__ u16 Asw[64 * 64];
    __shared__ u16 Bsw[64 * 64];
    const int K = 512;
    const int N = 512;
    int id = blockIdx.x + 8 * blockIdx.y;         // [0,1152)
    int l = (id & 7) * 144 + (id >> 3);           // bijective XCD remap
    int n0 = (l & 7) * 64;
    int m0 = (l >> 3) * 64;
    int tid = threadIdx.x;
    int lane = tid & 63, w = tid >> 6;
    int wm = w >> 1, wn = w & 1;
    int li = lane & 15, g = lane >> 4;
    f32x4 zero4 = {0.f, 0.f, 0.f, 0.f};
    f32x4 acc[2][2];
#pragma unroll
    for (int mi = 0; mi < 2; ++mi)
#pragma unroll
        for (int ni = 0; ni < 2; ++ni) acc[mi][ni] = zero4;

    for (int k0 = 0; k0 < K; k0 += 64) {
        __syncthreads();
#pragma unroll
        for (int p = 0; p < 2; ++p) {
            int ci = p * 256 + tid;
            int r = ci >> 3, j = ci & 7;
            int jj = j ^ (r & 7);
            gl_lds16(A  + (size_t)(m0 + r) * K + k0 + jj * 8, (char*)Asw + ci * 16);
            gl_lds16(BT + (size_t)(n0 + r) * K + k0 + jj * 8, (char*)Bsw + ci * 16);
        }
        __syncthreads();
#pragma unroll
        for (int ks = 0; ks < 2; ++ks) {
            bf16x8 af[2], bfr[2];
#pragma unroll
            for (int mi = 0; mi < 2; ++mi) {
                int r = wm * 32 + mi * 16 + li;
                int kc = ks * 4 + g;
                af[mi] = *(const bf16x8*)((const char*)Asw + r * 128 + ((kc ^ (r & 7)) * 16));
            }
#pragma unroll
            for (int ni = 0; ni < 2; ++ni) {
                int r = wn * 32 + ni * 16 + li;
                int kc = ks * 4 + g;
                bfr[ni] = *(const bf16x8*)((const char*)Bsw + r * 128 + ((kc ^ (r & 7)) * 16));
            }
#pragma unroll
            for (int mi = 0; mi < 2; ++mi)
#pragma unroll
                for (int ni = 0; ni < 2; ++ni)
                    acc[mi][ni] = __builtin_amdgcn_mfma_f32_16x16x32_bf16(af[mi], bfr[ni], acc[mi][ni], 0, 0, 0);
        }
    }
#pragma unroll
    for (int mi = 0; mi < 2; ++mi)
#pragma unroll
        for (int ni = 0; ni < 2; ++ni) {
#pragma unroll
            for (int r = 0; r < 4; ++r) {
                int row = m0 + wm * 32 + mi * 16 + g * 4 + r;
                int col = n0 + wn * 32 + ni * 16 + li;
                Cout[(size_t)row * N + col] = acc[mi][ni][r] + bias[col];
            }
        }
}

// ------------------------------------------------- differential windowed attention
// wave = (b,hkv,qh,mu,beta) handling both h2 heads; all loads lane-contiguous.
// K double-buffered with CLAMPED prefetch; NTT=2 paths also double-buffer V.
// Softmax scale pre-folded into Q; quadratic exp2.  [FROZEN — r15 configuration]
template <int A, int NTT>
__device__ __forceinline__ void load_k(const u16* __restrict__ kb, bf16x8 (&kf)[NTT][2], int lane) {
#pragma unroll
    for (int t = 0; t < NTT; ++t)
#pragma unroll
        for (int s = 0; s < 2; ++s)
            kf[t][s] = *(const bf16x8*)(kb + ((A + t) * 2 + s) * 512 + lane * 8);
}

template <int A, int NTT>
__device__ __forceinline__ void load_v(const u16* __restrict__ vb, uint2 (&ch)[4][NTT], int lane) {
#pragma unroll
    for (int dt = 0; dt < 4; ++dt)
#pragma unroll
        for (int t = 0; t < NTT; ++t)
            ch[dt][t] = *(const uint2*)(vb + ((dt * 3 + A + t) * 64 + lane) * 4);
}

template <int A, int NTT>
__device__ __forceinline__ void attn_core(
    const bf16x8 (&kf)[NTT][2], const uint2 (&ch)[4][NTT],
    const bf16x8 (&qf)[2][2], const float (&bmul)[3][4],
    f32x4 (&Oa)[2][4], float (&sum)[2]) {
    __builtin_amdgcn_s_setprio(1);
    U8 pa0[2], pa1[2];
#pragma unroll
    for (int h = 0; h < 2; ++h) {
        f32x4 S[NTT];
#pragma unroll
        for (int t = 0; t < NTT; ++t) {
            f32x4 z = {0.f, 0.f, 0.f, 0.f};
            z = __builtin_amdgcn_mfma_f32_16x16x32_bf16(kf[t][0], qf[h][0], z, 0, 0, 0);
            S[t] = __builtin_amdgcn_mfma_f32_16x16x32_bf16(kf[t][1], qf[h][1], z, 0, 0, 0);
        }
        uint32_t pk[NTT][2];
#pragma unroll
        for (int t = 0; t < NTT; ++t)
#pragma unroll
            for (int rp = 0; rp < 2; ++rp) {
                float p0 = exp2q(S[t][2 * rp])     * bmul[A + t][2 * rp];
                float p1 = exp2q(S[t][2 * rp + 1]) * bmul[A + t][2 * rp + 1];
                sum[h] += p0 + p1;
                pk[t][rp] = cvt_pk_bf16(p0, p1);
            }
        pa0[h].u[0] = pk[0][0]; pa0[h].u[1] = pk[0][1];
        pa0[h].u[2] = pk[1][0]; pa0[h].u[3] = pk[1][1];
        if (NTT == 3) { pa1[h].u[0] = pk[2][0]; pa1[h].u[1] = pk[2][1]; pa1[h].u[2] = 0; pa1[h].u[3] = 0; }
    }
#pragma unroll
    for (int dt = 0; dt < 4; ++dt) {
        union { bf16x8 v; uint2 q[2]; } vf0, vf1;
        vf0.q[0] = ch[dt][0]; vf0.q[1] = ch[dt][1];
        if (NTT == 3) { vf1.q[0] = ch[dt][2]; vf1.q[1] = ch[dt][2]; } // upper half x zero P
#pragma unroll
        for (int h = 0; h < 2; ++h) {
            Oa[h][dt] = __builtin_amdgcn_mfma_f32_16x16x32_bf16(pa0[h].v, vf0.v, Oa[h][dt], 0, 0, 0);
            if (NTT == 3)
                Oa[h][dt] = __builtin_amdgcn_mfma_f32_16x16x32_bf16(pa1[h].v, vf1.v, Oa[h][dt], 0, 0, 0);
        }
    }
    __builtin_amdgcn_s_setprio(0);
}

// NTT=3 path: K prefetched, V loaded in-iteration (VGPR budget).
template <int A, int NTT>
__device__ __forceinline__ void attn_step_local(
    const bf16x8 (&kf)[NTT][2], const u16* __restrict__ vb,
    const bf16x8 (&qf)[2][2], const float (&bmul)[3][4],
    f32x4 (&Oa)[2][4], float (&sum)[2], int lane) {
    uint2 ch[4][NTT];
    load_v<A, NTT>(vb, ch, lane);
    attn_core<A, NTT>(kf, ch, qf, bmul, Oa, sum);
}

template <int A, int NTT>
__device__ __forceinline__ void run_range(
    const u16* __restrict__ kp, const u16* __restrict__ vp, int n,
    const bf16x8 (&qf)[2][2], const float (&bmul)[3][4],
    f32x4 (&Oa)[2][4], float (&sum)[2], int lane) {
    bf16x8 kA[NTT][2], kB[NTT][2];
    load_k<A, NTT>(kp, kA, lane);           // tile 0
    int i = 0;
    for (; i + 2 <= n; i += 2) {
        load_k<A, NTT>(kp + 3072, kB, lane);                                   // tile i+1
        attn_step_local<A, NTT>(kA, vp, qf, bmul, Oa, sum, lane);              // tile i
        load_k<A, NTT>(kp + ((i + 3 <= n) ? 6144 : 3072), kA, lane);           // tile i+2, clamped
        attn_step_local<A, NTT>(kB, vp + 3072, qf, bmul, Oa, sum, lane);       // tile i+1
        kp += 6144; vp += 6144;
    }
    if (i < n) attn_step_local<A, NTT>(kA, vp, qf, bmul, Oa, sum, lane);       // tail (odd n)
}

// NTT=2 path: both K and V double-buffered with clamped prefetch.
template <int A>
__device__ __forceinline__ void run_range_pf(
    const u16* __restrict__ kp, const u16* __restrict__ vp, int n,
    const bf16x8 (&qf)[2][2], const float (&bmul)[3][4],
    f32x4 (&Oa)[2][4], float (&sum)[2], int lane) {
    bf16x8 kA[2][2], kB[2][2];
    uint2 vA[4][2], vB[4][2];
    load_k<A, 2>(kp, kA, lane);
    load_v<A, 2>(vp, vA, lane);
    int i = 0;
    for (; i + 2 <= n; i += 2) {
        load_k<A, 2>(kp + 3072, kB, lane);
        load_v<A, 2>(vp + 3072, vB, lane);
        attn_core<A, 2>(kA, vA, qf, bmul, Oa, sum);
        int adv = (i + 3 <= n) ? 6144 : 3072;   // clamped in-range
        load_k<A, 2>(kp + adv, kA, lane);
        load_v<A, 2>(vp + adv, vA, lane);
        attn_core<A, 2>(kB, vB, qf, bmul, Oa, sum);
        kp += 6144; vp += 6144;
    }
    if (i < n) attn_core<A, 2>(kA, vA, qf, bmul, Oa, sum);
}

__global__ __launch_bounds__(128) void k_attention(
    const u16* __restrict__ Q1, const u16* __restrict__ Q2,
    const u16* __restrict__ KF1, const u16* __restrict__ KF2,
    const u16* __restrict__ VF1, const u16* __restrict__ VF2,
    const float* __restrict__ lambda_p, u16* __restrict__ AOUT) {
    __shared__ float obuf[2][16][64];
    int tid = threadIdx.x;
    int lane = tid & 63, beta = tid >> 6;
    int li = lane & 15, g = lane >> 4;
    // XCD swizzle + central-first qh ordering (long blocks launch first)
    int hw = blockIdx.x;
    int l = (hw & 7) * 288 + (hw >> 3);
    int mu = l % 3, j = (l / 3) % 48, kvb = l / 144;
    int m2 = j >> 1;
    int qh = (j & 1) ? (23 - m2) : (24 + m2);   // bijective [0,48) -> [0,48)
    int hkv = kvb & 3, b = kvb >> 2;

    const u16* Qb = beta ? Q2 : Q1;

    bf16x8 qf[2][2];
#pragma unroll
    for (int h2 = 0; h2 < 2; ++h2)
#pragma unroll
        for (int s = 0; s < 2; ++s)
            qf[h2][s] = *(const bf16x8*)(Qb + ((size_t)(b * 8 + hkv * 2 + h2) * 2304
                            + qh * 48 + mu * 16 + li) * 64 + s * 32 + g * 8);

    float bmul[3][4];
    int qw = mu * 16 + li;
#pragma unroll
    for (int t = 0; t < 3; ++t)
#pragma unroll
        for (int r = 0; r < 4; ++r) {
            int kw = t * 16 + 4 * g + r;
            int dw = qw - kw; if (dw < 0) dw = -dw;
            bmul[t][r] = (dw <= 12) ? 1.0f : 0.0f;
        }

    f32x4 zero4 = {0.f, 0.f, 0.f, 0.f};
    f32x4 Oa[2][4];
#pragma unroll
    for (int h = 0; h < 2; ++h)
#pragma unroll
        for (int dt = 0; dt < 4; ++dt) Oa[h][dt] = zero4;
    float sum[2] = {0.f, 0.f};

    int kh0 = imax(0, qh - 12), kh1 = imin(47, qh + 12);
    int niter = kh1 - kh0 + 1;
    const u16* kp = (beta ? KF2 : KF1) + ((size_t)kvb * 48 + kh0) * 3072;
    const u16* vp = (beta ? VF2 : VF1) + ((size_t)kvb * 48 + kh0) * 3072;

    if (mu == 1)      run_range<0, 3>(kp, vp, niter, qf, bmul, Oa, sum, lane);
    else if (mu == 0) run_range_pf<0>(kp, vp, niter, qf, bmul, Oa, sum, lane);
    else              run_range_pf<1>(kp, vp, niter, qf, bmul, Oa, sum, lane);

    // finish row-sums: reduce over g groups, then fetch per-(4g+r) sums
    float inv[2][4];
#pragma unroll
    for (int h = 0; h < 2; ++h) {
        float s = sum[h];
        s += __shfl_xor(s, 16, 64);
        s += __shfl_xor(s, 32, 64);   // every lane: rowsum for q = li
#pragma unroll
        for (int r = 0; r < 4; ++r)
            inv[h][r] = 1.0f / __shfl(s, 4 * g + r, 64);
    }

    if (beta == 1) {
#pragma unroll
        for (int h = 0; h < 2; ++h)
#pragma unroll
            for (int dt = 0; dt < 4; ++dt)
#pragma unroll
                for (int r = 0; r < 4; ++r)
                    obuf[h][4 * g + r][dt * 16 + li] = Oa[h][dt][r] * inv[h][r];
    }
    __syncthreads();
    if (beta == 0) {
#pragma unroll
        for (int h = 0; h < 2; ++h) {
            float lam = 1.0f / (1.0f + expf(-lambda_p[hkv * 2 + h]));
#pragma unroll
            for (int dt = 0; dt < 4; ++dt)
#pragma unroll
                for (int r = 0; r < 4; ++r) {
                    float o1 = Oa[h][dt][r] * inv[h][r];
                    float o2 = obuf[h][4 * g + r][dt * 16 + li];
                    int n = qh * 48 + mu * 16 + 4 * g + r;
                    int colc = (hkv * 2 + h) * 64 + dt * 16 + li;
                    AOUT[((size_t)(b * 2304 + n)) * 512 + colc] = f2bf(o1 - lam * o2);
                }
        }
    }
}

// ---------------------------------------------------------------- launcher
extern "C" void kernel_launch(void* const* d_in, const int* in_sizes, int n_in,
                              void* d_out, int out_size, void* d_ws, size_t ws_size,
                              hipStream_t stream) {
    const float* x        = (const float*)d_in[0];
    const float* Wq       = (const float*)d_in[1];
    const float* Wk       = (const float*)d_in[2];
    const float* Wv1      = (const float*)d_in[3];
    const float* Wv2      = (const float*)d_in[4];
    const float* lambda_p = (const float*)d_in[5];
    const float* Wp       = (const float*)d_in[6];
    const float* bp       = (const float*)d_in[7];

    char* ws = (char*)d_ws;
    size_t off = 0;
    auto alloc = [&](size_t bytes) { char* p = ws + off; off += (bytes + 255) & ~(size_t)255; return p; };
    float* rope = (float*)alloc((size_t)2304 * 32 * 2 * 4);
    u16* XB     = (u16*)alloc((size_t)9216 * 512 * 2);
    u16* WCT    = (u16*)alloc((size_t)2048 * 512 * 2);
    u16* WPT    = (u16*)alloc((size_t)512 * 512 * 2);
    u16* Q1     = (u16*)alloc((size_t)4 * 8 * 2304 * 64 * 2);
    u16* Q2     = (u16*)alloc((size_t)4 * 8 * 2304 * 64 * 2);
    u16* KF1    = (u16*)alloc((size_t)16 * 48 * 3072 * 2);
    u16* KF2    = (u16*)alloc((size_t)16 * 48 * 3072 * 2);
    u16* VF1    = (u16*)alloc((size_t)16 * 48 * 3072 * 2);
    u16* VF2    = (u16*)alloc((size_t)16 * 48 * 3072 * 2);
    u16* AOUT   = (u16*)alloc((size_t)9216 * 512 * 2);

    k_prep<<<5216, 256, 0, stream>>>(x, Wq, Wk, Wv1, Wv2, Wp, rope, XB, WCT, WPT);
    k_gemm_qkv<<<dim3(16, 72), 256, 0, stream>>>(XB, WCT, rope, Q1, Q2, KF1, KF2, VF1, VF2);
    k_attention<<<2304, 128, 0, stream>>>(Q1, Q2, KF1, KF2, VF1, VF2, lambda_p, AOUT);
    k_gemm_o64<<<dim3(8, 144), 256, 0, stream>>>(AOUT, WPT, (float*)d_out, bp);
}

// Round 18
// 120.205 us; speedup vs baseline: 1.9665x; 1.0012x over previous
//
#include <hip/hip_runtime.h>
#include <stdint.h>

typedef unsigned short u16;
typedef __attribute__((ext_vector_type(8))) short bf16x8;
typedef __attribute__((ext_vector_type(4))) float f32x4;

#define LOG2E 1.4426950408889634f
#define QSCALE (0.125f * LOG2E)

__device__ __forceinline__ float bf2f(u16 u) {
    union { uint32_t i; float f; } v; v.i = ((uint32_t)u) << 16; return v.f;
}
__device__ __forceinline__ u16 f2bf(float f) {
    union { float f; uint32_t i; } v; v.f = f;
    uint32_t i = v.i;
    return (u16)((i + 0x7FFF + ((i >> 16) & 1)) >> 16);
}
__device__ __forceinline__ uint32_t cvt_pk_bf16(float a, float b) {
    uint32_t r;
    asm("v_cvt_pk_bf16_f32 %0, %1, %2" : "=v"(r) : "v"(a), "v"(b));
    return r;
}
__device__ __forceinline__ int imin(int a, int b) { return a < b ? a : b; }
__device__ __forceinline__ int imax(int a, int b) { return a > b ? a : b; }

__device__ __forceinline__ void gl_lds16(const void* g, void* l) {
    __builtin_amdgcn_global_load_lds(
        (const __attribute__((address_space(1))) uint32_t*)g,
        (__attribute__((address_space(3))) uint32_t*)l, 16, 0, 0);
}

// exp2(t) for |t| <= 0.19, tuned quadratic (odd-term absorbed into linear coeff);
// rel err <= ~1e-4, and the common-mode part cancels in softmax normalization.
__device__ __forceinline__ float exp2q(float t) {
    const float a = 0.6946474805f;
    const float b = 0.2402265069f;
    return fmaf(fmaf(b, t, a), t, 1.0f);
}

union U8 { bf16x8 v; uint32_t u[4]; };

// ---------------------------------------------------------------- fused prep
// blocks [0,288): rope table; [288,4896): x->bf16; [4896,5216): weight transpose.
__global__ void k_prep(const float* __restrict__ x,
                       const float* __restrict__ Wq, const float* __restrict__ Wk,
                       const float* __restrict__ Wv1, const float* __restrict__ Wv2,
                       const float* __restrict__ Wp,
                       float* __restrict__ tab, u16* __restrict__ xb,
                       u16* __restrict__ WCT, u16* __restrict__ WPT) {
    __shared__ u16 tile[64][65];
    int bid = blockIdx.x;
    if (bid < 288) {
        int t = bid * 256 + threadIdx.x;
        if (t >= 2304 * 32) return;
        int n = t >> 5, j = t & 31;
        int gh = n / 48, gw = n % 48;
        float f = (float)(j & 15);
        float coord = (j < 16) ? (float)gh : (float)gw;
        float inv = exp2f(-f * (13.287712379549449f / 16.0f)); // 10000^(-f/16)
        float th = coord * inv;
        tab[t * 2 + 0] = cosf(th);
        tab[t * 2 + 1] = sinf(th);
    } else if (bid < 4896) {
        int t = (bid - 288) * 256 + threadIdx.x;
        if (t >= 9216 * 512 / 4) return;
        float4 v = ((const float4*)x)[t];
        ushort4 o;
        o.x = f2bf(v.x); o.y = f2bf(v.y); o.z = f2bf(v.z); o.w = f2bf(v.w);
        ((ushort4*)xb)[t] = o;
    } else {
        int jb = bid - 4896;               // [0,320)
        int n0 = (jb % 40) * 64;
        int k0 = (jb / 40) * 64;
        int c = threadIdx.x & 63;
        int rr = threadIdx.x >> 6;
        const float* src; int stride; int roff; u16* dst; int nb;
        if (n0 < 1024)      { src = Wq;  stride = 1024; roff = 0;    dst = WCT; nb = n0; }
        else if (n0 < 1536) { src = Wk;  stride = 512;  roff = 1024; dst = WCT; nb = n0; }
        else if (n0 < 1792) { src = Wv1; stride = 256;  roff = 1536; dst = WCT; nb = n0; }
        else if (n0 < 2048) { src = Wv2; stride = 256;  roff = 1792; dst = WCT; nb = n0; }
        else                { src = Wp;  stride = 512;  roff = 2048; dst = WPT; nb = n0 - 2048; }
        int scol = n0 + c - roff;
#pragma unroll
        for (int i = 0; i < 16; ++i) {
            int k = rr * 16 + i;
            tile[c][k] = f2bf(src[(size_t)(k0 + k) * stride + scol]);
        }
        __syncthreads();
        int kk = threadIdx.x & 63;
        int c4 = threadIdx.x >> 6;
#pragma unroll
        for (int i = 0; i < 16; ++i) {
            int nl = c4 * 16 + i;
            dst[(size_t)(nb + nl) * 512 + k0 + kk] = tile[nl][kk];
        }
    }
}

// ---------------------------------------------------------------- fused QKV GEMM
// C = XB * WCT^T with fused epilogue: Q cols -> L2norm+RoPE (scaled by QSCALE) -> Q1/Q2;
// K cols -> L2norm+RoPE -> KF fragment layout; V cols -> VF fragment layout.
// XCD-aware remap: each XCD owns 9 contiguous m-tiles x all 16 n-tiles.
__global__ __launch_bounds__(256) void k_gemm_qkv(
    const u16* __restrict__ A, const u16* __restrict__ BT,
    const float* __restrict__ tab,
    u16* __restrict__ Q1, u16* __restrict__ Q2,
    u16* __restrict__ KF1, u16* __restrict__ KF2,
    u16* __restrict__ VF1, u16* __restrict__ VF2) {
    __shared__ u16 Asw[128 * 64];
    __shared__ u16 Bsw[128 * 64];
    const int K = 512;
    int id = blockIdx.x + 16 * blockIdx.y;        // [0,1152)
    int l = (id & 7) * 144 + (id >> 3);           // bijective XCD remap
    int n0 = (l & 15) * 128;
    int m0 = (l >> 4) * 128;
    int tid = threadIdx.x;
    int lane = tid & 63, w = tid >> 6;
    int wm = w >> 1, wn = w & 1;
    int li = lane & 15, g = lane >> 4;
    f32x4 zero4 = {0.f, 0.f, 0.f, 0.f};
    f32x4 acc[4][4];
#pragma unroll
    for (int mi = 0; mi < 4; ++mi)
#pragma unroll
        for (int ni = 0; ni < 4; ++ni) acc[mi][ni] = zero4;

    for (int k0 = 0; k0 < K; k0 += 64) {
        __syncthreads();
#pragma unroll
        for (int p = 0; p < 4; ++p) {
            int cidx = p * 256 + tid;
            int r = cidx >> 3, j = cidx & 7;
            int jj = j ^ (r & 7);
            gl_lds16(A  + (size_t)(m0 + r) * K + k0 + jj * 8, (char*)Asw + cidx * 16);
            gl_lds16(BT + (size_t)(n0 + r) * K + k0 + jj * 8, (char*)Bsw + cidx * 16);
        }
        __syncthreads();
#pragma unroll
        for (int ks = 0; ks < 2; ++ks) {
            bf16x8 af[4], bfr[4];
#pragma unroll
            for (int mi = 0; mi < 4; ++mi) {
                int r = wm * 64 + mi * 16 + li;
                int kc = ks * 4 + g;
                af[mi] = *(const bf16x8*)((const char*)Asw + r * 128 + ((kc ^ (r & 7)) * 16));
            }
#pragma unroll
            for (int ni = 0; ni < 4; ++ni) {
                int r = wn * 64 + ni * 16 + li;
                int kc = ks * 4 + g;
                bfr[ni] = *(const bf16x8*)((const char*)Bsw + r * 128 + ((kc ^ (r & 7)) * 16));
            }
#pragma unroll
            for (int mi = 0; mi < 4; ++mi)
#pragma unroll
                for (int ni = 0; ni < 4; ++ni)
                    acc[mi][ni] = __builtin_amdgcn_mfma_f32_16x16x32_bf16(af[mi], bfr[ni], acc[mi][ni], 0, 0, 0);
        }
    }

    // ------------- fused epilogue -------------
    int colbase = n0 + wn * 64;           // head-aligned 64-col block
    int b = m0 / 2304;                    // tile never straddles batch (2304 % 128 == 0)
    int nbase = (m0 % 2304) + wm * 64;

    if (colbase < 1536) {
        // Q or K: L2 norm over the 64-dim head vector + RoPE, then write.
        u16* out; int isK; size_t hb;
        if (colbase < 1024) {
            out = (colbase < 512) ? Q1 : Q2;
            int h = (colbase >> 6) & 7;
            hb = (size_t)(b * 8 + h) * 2304;
            isK = 0;
        } else {
            out = (colbase < 1280) ? KF1 : KF2;
            int hkv = ((colbase - 1024) >> 6) & 3;
            hb = (size_t)(b * 4 + hkv) * 48;
            isK = 1;
        }
        float qs = isK ? 1.0f : QSCALE;   // fold softmax scale into Q only
#pragma unroll
        for (int mi = 0; mi < 4; ++mi) {
            float rsq[4];
#pragma unroll
            for (int r = 0; r < 4; ++r) {
                float ss = 0.f;
#pragma unroll
                for (int ni = 0; ni < 4; ++ni) ss += acc[mi][ni][r] * acc[mi][ni][r];
                ss += __shfl_xor(ss, 1, 64);
                ss += __shfl_xor(ss, 2, 64);
                ss += __shfl_xor(ss, 4, 64);
                ss += __shfl_xor(ss, 8, 64);
                rsq[r] = qs / sqrtf(ss + 1e-12f);
            }
#pragma unroll
            for (int r = 0; r < 4; ++r) {
                int n = nbase + mi * 16 + g * 4 + r;
                float2 cs0 = *(const float2*)(tab + ((size_t)n * 32 + li) * 2);
                float2 cs1 = *(const float2*)(tab + ((size_t)n * 32 + 16 + li) * 2);
                float y[4];
#pragma unroll
                for (int ni = 0; ni < 4; ++ni) {
                    float c = (ni & 1) ? cs1.x : cs0.x;
                    float s = (ni & 1) ? cs1.y : cs0.y;
                    float p = acc[mi][ni ^ 2][r];
                    float t = (ni < 2) ? (acc[mi][ni][r] * c - p * s)
                                       : (acc[mi][ni][r] * c + p * s);
                    y[ni] = t * rsq[r];
                }
                if (!isK) {
                    size_t obase = (hb + n) * 64;
#pragma unroll
                    for (int ni = 0; ni < 4; ++ni)
                        out[obase + ni * 16 + li] = f2bf(y[ni]);
                } else {
                    int kh = n / 48, r48 = n % 48;
                    int kt = r48 >> 4, lq = r48 & 15;
                    size_t base = (hb + kh) * 3072;
#pragma unroll
                    for (int ni = 0; ni < 4; ++ni) {
                        int sC = ni >> 1;
                        int gg = ((ni & 1) << 1) + (li >> 3);
                        int e = li & 7;
                        out[base + (size_t)(((kt * 2 + sC) * 64 + gg * 16 + lq) * 8 + e)] = f2bf(y[ni]);
                    }
                }
            }
        }
    } else {
        // V: no norm/rope; pack straight into VF fragment layout.
        u16* out = (colbase < 1792) ? VF1 : VF2;
        int hkv = ((colbase - 1536) >> 6) & 3;
        size_t hb = (size_t)(b * 4 + hkv) * 48;
#pragma unroll
        for (int mi = 0; mi < 4; ++mi) {
            int n4 = nbase + mi * 16 + g * 4;       // 4 consecutive tokens, 4-aligned
            int kh = n4 / 48, r48 = n4 % 48;
            int grp = r48 >> 2;
            int kt = grp >> 2, gp = grp & 3;
            size_t base = (hb + kh) * 3072;
#pragma unroll
            for (int ni = 0; ni < 4; ++ni) {
                uint2 val;
                val.x = cvt_pk_bf16(acc[mi][ni][0], acc[mi][ni][1]);
                val.y = cvt_pk_bf16(acc[mi][ni][2], acc[mi][ni][3]);
                *(uint2*)(out + base + (size_t)(((ni * 3 + kt) * 64 + gp * 16 + li) * 4)) = val;
            }
        }
    }
}

// ---------------------------------------------------------------- out GEMM, 64x64 tiles
// XCD-aware remap: each XCD owns 18 contiguous m-tiles x all 8 n-tiles.
__global__ __launch_bounds__(256) void k_gemm_o64(
    const u16* __restrict__ A, const u16* __restrict__ BT,
    float* __restrict__ Cout, const float* __restrict__ bias) {
    __shared__ u16 Asw[64 * 64];
    __shared__ u16 Bsw[64 * 64];
    const int K = 512;
    const int N = 512;
    int id = blockIdx.x + 8 * blockIdx.y;         // [0,1152)
    int l = (id & 7) * 144 + (id >> 3);           // bijective XCD remap
    int n0 = (l & 7) * 64;
    int m0 = (l >> 3) * 64;
    int tid = threadIdx.x;
    int lane = tid & 63, w = tid >> 6;
    int wm = w >> 1, wn = w & 1;
    int li = lane & 15, g = lane >> 4;
    f32x4 zero4 = {0.f, 0.f, 0.f, 0.f};
    f32x4 acc[2][2];
#pragma unroll
    for (int mi = 0; mi < 2; ++mi)
#pragma unroll
        for (int ni = 0; ni < 2; ++ni) acc[mi][ni] = zero4;

    for (int k0 = 0; k0 < K; k0 += 64) {
        __syncthreads();
#pragma unroll
        for (int p = 0; p < 2; ++p) {
            int ci = p * 256 + tid;
            int r = ci >> 3, j = ci & 7;
            int jj = j ^ (r & 7);
            gl_lds16(A  + (size_t)(m0 + r) * K + k0 + jj * 8, (char*)Asw + ci * 16);
            gl_lds16(BT + (size_t)(n0 + r) * K + k0 + jj * 8, (char*)Bsw + ci * 16);
        }
        __syncthreads();
#pragma unroll
        for (int ks = 0; ks < 2; ++ks) {
            bf16x8 af[2], bfr[2];
#pragma unroll
            for (int mi = 0; mi < 2; ++mi) {
                int r = wm * 32 + mi * 16 + li;
                int kc = ks * 4 + g;
                af[mi] = *(const bf16x8*)((const char*)Asw + r * 128 + ((kc ^ (r & 7)) * 16));
            }
#pragma unroll
            for (int ni = 0; ni < 2; ++ni) {
                int r = wn * 32 + ni * 16 + li;
                int kc = ks * 4 + g;
                bfr[ni] = *(const bf16x8*)((const char*)Bsw + r * 128 + ((kc ^ (r & 7)) * 16));
            }
#pragma unroll
            for (int mi = 0; mi < 2; ++mi)
#pragma unroll
                for (int ni = 0; ni < 2; ++ni)
                    acc[mi][ni] = __builtin_amdgcn_mfma_f32_16x16x32_bf16(af[mi], bfr[ni], acc[mi][ni], 0, 0, 0);
        }
    }
#pragma unroll
    for (int mi = 0; mi < 2; ++mi)
#pragma unroll
        for (int ni = 0; ni < 2; ++ni) {
#pragma unroll
            for (int r = 0; r < 4; ++r) {
                int row = m0 + wm * 32 + mi * 16 + g * 4 + r;
                int col = n0 + wn * 32 + ni * 16 + li;
                Cout[(size_t)row * N + col] = acc[mi][ni][r] + bias[col];
            }
        }
}

// ------------------------------------------------- differential windowed attention
// wave = (b,hkv,qh,mu,beta) handling both h2 heads; all loads lane-contiguous.
// K double-buffered with CLAMPED prefetch; NTT=2 paths also double-buffer V.
// Softmax scale pre-folded into Q; quadratic exp2.  [FROZEN — r15 configuration]
template <int A, int NTT>
__device__ __forceinline__ void load_k(const u16* __restrict__ kb, bf16x8 (&kf)[NTT][2], int lane) {
#pragma unroll
    for (int t = 0; t < NTT; ++t)
#pragma unroll
        for (int s = 0; s < 2; ++s)
            kf[t][s] = *(const bf16x8*)(kb + ((A + t) * 2 + s) * 512 + lane * 8);
}

template <int A, int NTT>
__device__ __forceinline__ void load_v(const u16* __restrict__ vb, uint2 (&ch)[4][NTT], int lane) {
#pragma unroll
    for (int dt = 0; dt < 4; ++dt)
#pragma unroll
        for (int t = 0; t < NTT; ++t)
            ch[dt][t] = *(const uint2*)(vb + ((dt * 3 + A + t) * 64 + lane) * 4);
}

template <int A, int NTT>
__device__ __forceinline__ void attn_core(
    const bf16x8 (&kf)[NTT][2], const uint2 (&ch)[4][NTT],
    const bf16x8 (&qf)[2][2], const float (&bmul)[3][4],
    f32x4 (&Oa)[2][4], float (&sum)[2]) {
    __builtin_amdgcn_s_setprio(1);
    U8 pa0[2], pa1[2];
#pragma unroll
    for (int h = 0; h < 2; ++h) {
        f32x4 S[NTT];
#pragma unroll
        for (int t = 0; t < NTT; ++t) {
            f32x4 z = {0.f, 0.f, 0.f, 0.f};
            z = __builtin_amdgcn_mfma_f32_16x16x32_bf16(kf[t][0], qf[h][0], z, 0, 0, 0);
            S[t] = __builtin_amdgcn_mfma_f32_16x16x32_bf16(kf[t][1], qf[h][1], z, 0, 0, 0);
        }
        uint32_t pk[NTT][2];
#pragma unroll
        for (int t = 0; t < NTT; ++t)
#pragma unroll
            for (int rp = 0; rp < 2; ++rp) {
                float p0 = exp2q(S[t][2 * rp])     * bmul[A + t][2 * rp];
                float p1 = exp2q(S[t][2 * rp + 1]) * bmul[A + t][2 * rp + 1];
                sum[h] += p0 + p1;
                pk[t][rp] = cvt_pk_bf16(p0, p1);
            }
        pa0[h].u[0] = pk[0][0]; pa0[h].u[1] = pk[0][1];
        pa0[h].u[2] = pk[1][0]; pa0[h].u[3] = pk[1][1];
        if (NTT == 3) { pa1[h].u[0] = pk[2][0]; pa1[h].u[1] = pk[2][1]; pa1[h].u[2] = 0; pa1[h].u[3] = 0; }
    }
#pragma unroll
    for (int dt = 0; dt < 4; ++dt) {
        union { bf16x8 v; uint2 q[2]; } vf0, vf1;
        vf0.q[0] = ch[dt][0]; vf0.q[1] = ch[dt][1];
        if (NTT == 3) { vf1.q[0] = ch[dt][2]; vf1.q[1] = ch[dt][2]; } // upper half x zero P
#pragma unroll
        for (int h = 0; h < 2; ++h) {
            Oa[h][dt] = __builtin_amdgcn_mfma_f32_16x16x32_bf16(pa0[h].v, vf0.v, Oa[h][dt], 0, 0, 0);
            if (NTT == 3)
                Oa[h][dt] = __builtin_amdgcn_mfma_f32_16x16x32_bf16(pa1[h].v, vf1.v, Oa[h][dt], 0, 0, 0);
        }
    }
    __builtin_amdgcn_s_setprio(0);
}

// NTT=3 path: K prefetched, V loaded in-iteration (VGPR budget).
template <int A, int NTT>
__device__ __forceinline__ void attn_step_local(
    const bf16x8 (&kf)[NTT][2], const u16* __restrict__ vb,
    const bf16x8 (&qf)[2][2], const float (&bmul)[3][4],
    f32x4 (&Oa)[2][4], float (&sum)[2], int lane) {
    uint2 ch[4][NTT];
    load_v<A, NTT>(vb, ch, lane);
    attn_core<A, NTT>(kf, ch, qf, bmul, Oa, sum);
}

template <int A, int NTT>
__device__ __forceinline__ void run_range(
    const u16* __restrict__ kp, const u16* __restrict__ vp, int n,
    const bf16x8 (&qf)[2][2], const float (&bmul)[3][4],
    f32x4 (&Oa)[2][4], float (&sum)[2], int lane) {
    bf16x8 kA[NTT][2], kB[NTT][2];
    load_k<A, NTT>(kp, kA, lane);           // tile 0
    int i = 0;
    for (; i + 2 <= n; i += 2) {
        load_k<A, NTT>(kp + 3072, kB, lane);                                   // tile i+1
        attn_step_local<A, NTT>(kA, vp, qf, bmul, Oa, sum, lane);              // tile i
        load_k<A, NTT>(kp + ((i + 3 <= n) ? 6144 : 3072), kA, lane);           // tile i+2, clamped
        attn_step_local<A, NTT>(kB, vp + 3072, qf, bmul, Oa, sum, lane);       // tile i+1
        kp += 6144; vp += 6144;
    }
    if (i < n) attn_step_local<A, NTT>(kA, vp, qf, bmul, Oa, sum, lane);       // tail (odd n)
}

// NTT=2 path: both K and V double-buffered with clamped prefetch.
template <int A>
__device__ __forceinline__ void run_range_pf(
    const u16* __restrict__ kp, const u16* __restrict__ vp, int n,
    const bf16x8 (&qf)[2][2], const float (&bmul)[3][4],
    f32x4 (&Oa)[2][4], float (&sum)[2], int lane) {
    bf16x8 kA[2][2], kB[2][2];
    uint2 vA[4][2], vB[4][2];
    load_k<A, 2>(kp, kA, lane);
    load_v<A, 2>(vp, vA, lane);
    int i = 0;
    for (; i + 2 <= n; i += 2) {
        load_k<A, 2>(kp + 3072, kB, lane);
        load_v<A, 2>(vp + 3072, vB, lane);
        attn_core<A, 2>(kA, vA, qf, bmul, Oa, sum);
        int adv = (i + 3 <= n) ? 6144 : 3072;   // clamped in-range
        load_k<A, 2>(kp + adv, kA, lane);
        load_v<A, 2>(vp + adv, vA, lane);
        attn_core<A, 2>(kB, vB, qf, bmul, Oa, sum);
        kp += 6144; vp += 6144;
    }
    if (i < n) attn_core<A, 2>(kA, vA, qf, bmul, Oa, sum);
}

__global__ __launch_bounds__(128) void k_attention(
    const u16* __restrict__ Q1, const u16* __restrict__ Q2,
    const u16* __restrict__ KF1, const u16* __restrict__ KF2,
    const u16* __restrict__ VF1, const u16* __restrict__ VF2,
    const float* __restrict__ lambda_p, u16* __restrict__ AOUT) {
    __shared__ float obuf[2][16][64];
    int tid = threadIdx.x;
    int lane = tid & 63, beta = tid >> 6;
    int li = lane & 15, g = lane >> 4;
    // XCD swizzle + central-first qh ordering (long blocks launch first)
    int hw = blockIdx.x;
    int l = (hw & 7) * 288 + (hw >> 3);
    int mu = l % 3, j = (l / 3) % 48, kvb = l / 144;
    int m2 = j >> 1;
    int qh = (j & 1) ? (23 - m2) : (24 + m2);   // bijective [0,48) -> [0,48)
    int hkv = kvb & 3, b = kvb >> 2;

    const u16* Qb = beta ? Q2 : Q1;

    bf16x8 qf[2][2];
#pragma unroll
    for (int h2 = 0; h2 < 2; ++h2)
#pragma unroll
        for (int s = 0; s < 2; ++s)
            qf[h2][s] = *(const bf16x8*)(Qb + ((size_t)(b * 8 + hkv * 2 + h2) * 2304
                            + qh * 48 + mu * 16 + li) * 64 + s * 32 + g * 8);

    float bmul[3][4];
    int qw = mu * 16 + li;
#pragma unroll
    for (int t = 0; t < 3; ++t)
#pragma unroll
        for (int r = 0; r < 4; ++r) {
            int kw = t * 16 + 4 * g + r;
            int dw = qw - kw; if (dw < 0) dw = -dw;
            bmul[t][r] = (dw <= 12) ? 1.0f : 0.0f;
        }

    f32x4 zero4 = {0.f, 0.f, 0.f, 0.f};
    f32x4 Oa[2][4];
#pragma unroll
    for (int h = 0; h < 2; ++h)
#pragma unroll
        for (int dt = 0; dt < 4; ++dt) Oa[h][dt] = zero4;
    float sum[2] = {0.f, 0.f};

    int kh0 = imax(0, qh - 12), kh1 = imin(47, qh + 12);
    int niter = kh1 - kh0 + 1;
    const u16* kp = (beta ? KF2 : KF1) + ((size_t)kvb * 48 + kh0) * 3072;
    const u16* vp = (beta ? VF2 : VF1) + ((size_t)kvb * 48 + kh0) * 3072;

    if (mu == 1)      run_range<0, 3>(kp, vp, niter, qf, bmul, Oa, sum, lane);
    else if (mu == 0) run_range_pf<0>(kp, vp, niter, qf, bmul, Oa, sum, lane);
    else              run_range_pf<1>(kp, vp, niter, qf, bmul, Oa, sum, lane);

    // finish row-sums: reduce over g groups, then fetch per-(4g+r) sums
    float inv[2][4];
#pragma unroll
    for (int h = 0; h < 2; ++h) {
        float s = sum[h];
        s += __shfl_xor(s, 16, 64);
        s += __shfl_xor(s, 32, 64);   // every lane: rowsum for q = li
#pragma unroll
        for (int r = 0; r < 4; ++r)
            inv[h][r] = 1.0f / __shfl(s, 4 * g + r, 64);
    }

    if (beta == 1) {
#pragma unroll
        for (int h = 0; h < 2; ++h)
#pragma unroll
            for (int dt = 0; dt < 4; ++dt)
#pragma unroll
                for (int r = 0; r < 4; ++r)
                    obuf[h][4 * g + r][dt * 16 + li] = Oa[h][dt][r] * inv[h][r];
    }
    __syncthreads();
    if (beta == 0) {
#pragma unroll
        for (int h = 0; h < 2; ++h) {
            float lam = 1.0f / (1.0f + expf(-lambda_p[hkv * 2 + h]));
#pragma unroll
            for (int dt = 0; dt < 4; ++dt)
#pragma unroll
                for (int r = 0; r < 4; ++r) {
                    float o1 = Oa[h][dt][r] * inv[h][r];
                    float o2 = obuf[h][4 * g + r][dt * 16 + li];
                    int n = qh * 48 + mu * 16 + 4 * g + r;
                    int colc = (hkv * 2 + h) * 64 + dt * 16 + li;
                    AOUT[((size_t)(b * 2304 + n)) * 512 + colc] = f2bf(o1 - lam * o2);
                }
        }
    }
}

// ---------------------------------------------------------------- launcher
extern "C" void kernel_launch(void* const* d_in, const int* in_sizes, int n_in,
                              void* d_out, int out_size, void* d_ws, size_t ws_size,
                              hipStream_t stream) {
    const float* x        = (const float*)d_in[0];
    const float* Wq       = (const float*)d_in[1];
    const float* Wk       = (const float*)d_in[2];
    const float* Wv1      = (const float*)d_in[3];
    const float* Wv2      = (const float*)d_in[4];
    const float* lambda_p = (const float*)d_in[5];
    const float* Wp       = (const float*)d_in[6];
    const float* bp       = (const float*)d_in[7];

    char* ws = (char*)d_ws;
    size_t off = 0;
    auto alloc = [&](size_t bytes) { char* p = ws + off; off += (bytes + 255) & ~(size_t)255; return p; };
    float* rope = (float*)alloc((size_t)2304 * 32 * 2 * 4);
    u16* XB     = (u16*)alloc((size_t)9216 * 512 * 2);
    u16* WCT    = (u16*)alloc((size_t)2048 * 512 * 2);
    u16* WPT    = (u16*)alloc((size_t)512 * 512 * 2);
    u16* Q1     = (u16*)alloc((size_t)4 * 8 * 2304 * 64 * 2);
    u16* Q2     = (u16*)alloc((size_t)4 * 8 * 2304 * 64 * 2);
    u16* KF1    = (u16*)alloc((size_t)16 * 48 * 3072 * 2);
    u16* KF2    = (u16*)alloc((size_t)16 * 48 * 3072 * 2);
    u16* VF1    = (u16*)alloc((size_t)16 * 48 * 3072 * 2);
    u16* VF2    = (u16*)alloc((size_t)16 * 48 * 3072 * 2);
    u16* AOUT   = (u16*)alloc((size_t)9216 * 512 * 2);

    k_prep<<<5216, 256, 0, stream>>>(x, Wq, Wk, Wv1, Wv2, Wp, rope, XB, WCT, WPT);
    k_gemm_qkv<<<dim3(16, 72), 256, 0, stream>>>(XB, WCT, rope, Q1, Q2, KF1, KF2, VF1, VF2);
    k_attention<<<2304, 128, 0, stream>>>(Q1, Q2, KF1, KF2, VF1, VF2, lambda_p, AOUT);
    k_gemm_o64<<<dim3(8, 144), 256, 0, stream>>>(AOUT, WPT, (float*)d_out, bp);
}